// Round 12
// baseline (516.783 us; speedup 1.0000x reference)
//
#include <hip/hip_runtime.h>

#define BB 32
#define LLAYERS 12
#define HDIM 768
#define NHEAD 12
#define DHEAD 64
#define SEQ 197
#define IND 800
#define NOUT 1000
#define EPSF 1e-5f
#define NTOK (BB * SEQ)     // 6304
#define NPATCH (BB * 196)   // 6272
#define SCALE 0.125f        // 1/sqrt(64)

typedef __attribute__((ext_vector_type(4))) float f32x4;
typedef __attribute__((ext_vector_type(8))) short short8;

static __device__ __forceinline__ ushort f2bf(float f) {
    union { float f; unsigned u; } v; v.f = f;
    unsigned r = v.u + 0x7FFFu + ((v.u >> 16) & 1u);   // round-to-nearest-even
    return (ushort)(r >> 16);
}

static __device__ __forceinline__ void gload_lds16(const void* g, void* l) {
    __builtin_amdgcn_global_load_lds(
        (const __attribute__((address_space(1))) void*)g,
        (__attribute__((address_space(3))) void*)l, 16, 0, 0);
}

// ---------------------------------------------------------------------------
// K0: fused prep — map_w cvt (blocks 0..599), wqkv swizzle (600..1463),
// pos table (1464..1660), cls rows (1661..1692). All independent.
// ---------------------------------------------------------------------------
__global__ __launch_bounds__(256) void k_prep(
    const float* __restrict__ map_w, ushort* __restrict__ Wbf,
    const float* __restrict__ wq, const float* __restrict__ wk,
    const float* __restrict__ wv, ushort* __restrict__ Wswz,
    float* __restrict__ pos, const float* __restrict__ cls_tok,
    float* __restrict__ tok)
{
    int b = blockIdx.x;
    if (b < 600) {
        int i = b * 256 + threadIdx.x;
        if (i < (HDIM * IND) / 4) {
            float4 v = *(const float4*)&map_w[i * 4];
            ushort4 u = {f2bf(v.x), f2bf(v.y), f2bf(v.z), f2bf(v.w)};
            *(ushort4*)&Wbf[i * 4] = u;
        }
    } else if (b < 1464) {
        int t = (b - 600) * 256 + threadIdx.x;     // < 3*144*512 exactly
        int lane = t & 63;
        int rest = t >> 6;
        int ktnt = rest & 7;
        int mlh = rest >> 3;
        int h = mlh % 12, ml = mlh / 12;
        int l = ml % 12, m = ml / 12;
        int nt = ktnt & 3, kt = ktnt >> 2;
        int e = nt * 16 + (lane & 15);
        int d = kt * 32 + (lane >> 4) * 8;
        const float* src = ((m == 0) ? wq : (m == 1) ? wk : wv)
                           + (((long)l * 12 + h) * 64 + e) * 64 + d;
        float4 a = *(const float4*)src;
        float4 bb = *(const float4*)(src + 4);
        short8 u;
        u[0] = (short)f2bf(a.x); u[1] = (short)f2bf(a.y);
        u[2] = (short)f2bf(a.z); u[3] = (short)f2bf(a.w);
        u[4] = (short)f2bf(bb.x); u[5] = (short)f2bf(bb.y);
        u[6] = (short)f2bf(bb.z); u[7] = (short)f2bf(bb.w);
        *(short8*)&Wswz[(long)mlh * 4096 + ktnt * 512 + lane * 8] = u;
    } else if (b < 1661) {
        int s = b - 1464;
        for (int e = threadIdx.x; e < HDIM; e += 256) {
            float freq = expf((float)(e & ~1) * (-9.210340371976184f / 768.0f));
            float ang = (float)s * freq;
            pos[s * HDIM + e] = (e & 1) ? cosf(ang) : sinf(ang);
        }
    } else {
        int n = b - 1661;                          // 32 cls rows; pos[0,e]=e&1
        for (int e = threadIdx.x; e < HDIM; e += 256)
            tok[(long)n * SEQ * HDIM + e] = cls_tok[e] + ((e & 1) ? 1.0f : 0.0f);
    }
}

// ---------------------------------------------------------------------------
// K1: conv + BN + ReLU + patchify -> Xbf. 2 patches/block, 320 threads.
// R8 version: stride-21 rows give ph-bank spread {0,20,8,28,16} — measured
// ZERO bank conflicts. Do NOT pad (22: 5-way alias; 24: 5-way alias).
// ---------------------------------------------------------------------------
__global__ __launch_bounds__(320) void k_conv_patch(
    const float* __restrict__ img, const float* __restrict__ cw,
    const float* __restrict__ cb, const float* __restrict__ bg,
    const float* __restrict__ bbias, const float* __restrict__ bm,
    const float* __restrict__ bvv, ushort* __restrict__ X)
{
    __shared__ float tile[2][3][21][21];
    __shared__ float w[2400];
    __shared__ float scale[32], shift[32];
    int tid = threadIdx.x;

    for (int i = tid; i < 2400; i += 320) w[i] = cw[i];
    if (tid < 32) {
        float sc = bg[tid] * rsqrtf(bvv[tid] + EPSF);
        scale[tid] = sc;
        shift[tid] = (cb[tid] - bm[tid]) * sc + bbias[tid];
    }
    for (int i = tid; i < 2 * 3 * 441; i += 320) {
        int pp = i / 1323, j = i % 1323;
        int c = j / 441, r = (j / 21) % 21, cc = j % 21;
        int gp = blockIdx.x * 2 + pp;
        int n = gp / 196, p = gp % 196;
        int h0 = (p / 14) * 20 - 1, w0 = (p % 14) * 20 - 1;
        int gh = h0 + r, gw = w0 + cc;
        float v = 0.f;
        if (gh >= 0 && gh < 280 && gw >= 0 && gw < 280)
            v = img[((long)(n * 3 + c) * 280 + gh) * 280 + gw];
        tile[pp][c][r][cc] = v;
    }
    __syncthreads();

    int pp = tid / 160, u = tid % 160;
    int c = u / 5, ph = u % 5;
    float acc[5] = {0.f, 0.f, 0.f, 0.f, 0.f};
    const float* wp = &w[c * 75];
    #pragma unroll
    for (int ci = 0; ci < 3; ci++) {
        #pragma unroll
        for (int kh = 0; kh < 5; kh++) {
            const float* row = &tile[pp][ci][ph * 4 + kh][0];
            float rv[21];
            #pragma unroll
            for (int j = 0; j < 21; j++) rv[j] = row[j];
            #pragma unroll
            for (int kw = 0; kw < 5; kw++) {
                float wv = wp[ci * 25 + kh * 5 + kw];
                #pragma unroll
                for (int pw = 0; pw < 5; pw++)
                    acc[pw] += rv[pw * 4 + kw] * wv;
            }
        }
    }
    int gp = blockIdx.x * 2 + pp;
    long ob = (long)gp * 800 + c * 25 + ph * 5;
    #pragma unroll
    for (int pw = 0; pw < 5; pw++) {
        float val = acc[pw] * scale[c] + shift[c];
        X[ob + pw] = f2bf(fmaxf(val, 0.f));
    }
}

// ---------------------------------------------------------------------------
// K2: patch embed GEMM, bf16 MFMA
// ---------------------------------------------------------------------------
__global__ __launch_bounds__(256, 2) void k_embed(
    const ushort* __restrict__ Xg, const ushort* __restrict__ Wg,
    const float* __restrict__ bias, const float* __restrict__ pos,
    float* __restrict__ tok)
{
    __shared__ __align__(16) ushort As[128 * 32];
    __shared__ __align__(16) ushort Bs[64 * 32];
    int m0 = blockIdx.x * 128, e0 = blockIdx.y * 64;
    int tid = threadIdx.x, lane = tid & 63, wave = tid >> 6;
    int col = lane & 15, quad = lane >> 4;
    int wm = (wave & 1) * 64, wn = (wave >> 1) * 32;
    int lr = lane >> 2, lc = (lane & 3) * 8;
    f32x4 zero4 = {0.f, 0.f, 0.f, 0.f};
    f32x4 acc[4][2];
    #pragma unroll
    for (int mt = 0; mt < 4; mt++)
        #pragma unroll
        for (int nt = 0; nt < 2; nt++) acc[mt][nt] = zero4;

    for (int k0 = 0; k0 < 800; k0 += 32) {
        __syncthreads();
        #pragma unroll
        for (int i = 0; i < 2; i++) {
            int c = wave * 2 + i;
            gload_lds16(&Xg[(long)(m0 + c * 16 + lr) * 800 + k0 + lc], &As[c * 512]);
        }
        {
            int c = wave;
            gload_lds16(&Wg[(long)(e0 + c * 16 + lr) * 800 + k0 + lc], &Bs[c * 512]);
        }
        __syncthreads();
        short8 a[4], b[2];
        #pragma unroll
        for (int mt = 0; mt < 4; mt++)
            a[mt] = *(const short8*)&As[(wm + mt * 16 + col) * 32 + quad * 8];
        #pragma unroll
        for (int nt = 0; nt < 2; nt++)
            b[nt] = *(const short8*)&Bs[(wn + nt * 16 + col) * 32 + quad * 8];
        #pragma unroll
        for (int mt = 0; mt < 4; mt++)
            #pragma unroll
            for (int nt = 0; nt < 2; nt++)
                acc[mt][nt] = __builtin_amdgcn_mfma_f32_16x16x32_bf16(a[mt], b[nt], acc[mt][nt], 0, 0, 0);
    }
    #pragma unroll
    for (int mt = 0; mt < 4; mt++) {
        #pragma unroll
        for (int r = 0; r < 4; r++) {
            int m = m0 + wm + mt * 16 + quad * 4 + r;
            int n = m / 196, s = m - n * 196 + 1;
            long rowb = ((long)n * SEQ + s) * HDIM;
            #pragma unroll
            for (int nt = 0; nt < 2; nt++) {
                int e = e0 + wn + nt * 16 + col;
                tok[rowb + e] = acc[mt][nt][r] + bias[e] + pos[s * HDIM + e];
            }
        }
    }
}

// ---------------------------------------------------------------------------
// K3: initial LN partial-stats (layer 0)
// ---------------------------------------------------------------------------
__global__ __launch_bounds__(256) void k_lnstats0(
    const float* __restrict__ tok, float* __restrict__ stats_out)
{
    int tid = threadIdx.x, lane = tid & 63, wave = tid >> 6;
    int row = blockIdx.x * 4 + wave;          // NTOK = 4*1576 exact
    const float* p = tok + (long)row * HDIM;
    float s = 0.f, sq = 0.f;
    #pragma unroll
    for (int k = 0; k < 3; k++) {
        float4 v = *(const float4*)&p[k * 256 + lane * 4];
        s += v.x + v.y + v.z + v.w;
        sq += v.x * v.x + v.y * v.y + v.z * v.z + v.w * v.w;
    }
    #pragma unroll
    for (int off = 1; off < 64; off <<= 1) {
        s += __shfl_xor(s, off);
        sq += __shfl_xor(sq, off);
    }
    float* sp = &stats_out[(long)row * 24];
    if (lane == 0) { sp[0] = s; sp[1] = sq; }
    if (lane >= 2 && lane < 24) sp[lane] = 0.f;
}

// ---------------------------------------------------------------------------
// K4: FUSED transformer layer — 512 thr = 8 waves, 2 blocks/CU (~81 KB LDS).
// Q/K projections operand-swapped (packed b64 LDS stores). Scores ALSO
// operand-swapped: sc = K·Q^T -> D[key][query], making P stores packed
// ushort4 and the softmax a per-lane serial reduce + 2-step cross-quad
// shuffle. grid (12, 32).
// ---------------------------------------------------------------------------
__global__ __launch_bounds__(512, 4) void k_layer(
    float* __restrict__ tok,
    const float* __restrict__ stats_in, float* __restrict__ stats_out,
    const float* __restrict__ lng, const float* __restrict__ lnb,
    const ushort* __restrict__ wqs, const float* __restrict__ bqp,
    const ushort* __restrict__ wks, const float* __restrict__ bkp,
    const ushort* __restrict__ wvs, const float* __restrict__ bvp)
{
    __shared__ __align__(16) ushort Ks[208 * 72];   // 29.9 KB
    __shared__ __align__(16) ushort Vt[64 * 232];   // 29.7 KB
    __shared__ __align__(16) ushort Ps[8][16 * 72]; // 18.4 KB per-wave scratch
    __shared__ float smu[208], srstd[208];
    __shared__ __align__(16) float bias[3][64];
    __shared__ float lngs[64], lnbs[64];

    int h = blockIdx.x, n = blockIdx.y;
    int tid = threadIdx.x, lane = tid & 63, wave = tid >> 6;   // wave 0..7
    int col = lane & 15, quad = lane >> 4;
    int kq = quad * 4;                // key sub-offset after score swap
    f32x4 zero4 = {0.f, 0.f, 0.f, 0.f};

    // ---- phase 1: bias + ln params + per-row stats reduce + Vt pad ----
    if (tid < 192) {
        int m = tid >> 6, e = tid & 63;
        bias[m][e] = ((m == 0) ? bqp : (m == 1) ? bkp : bvp)[h * 64 + e];
    } else if (tid < 256) {
        lngs[tid - 192] = lng[h * 64 + tid - 192];
    } else if (tid < 320) {
        lnbs[tid - 256] = lnb[h * 64 + tid - 256];
    }
    for (int r = tid; r < SEQ; r += 512) {
        const float* sp = &stats_in[((long)n * SEQ + r) * 24];
        float s = 0.f, sq = 0.f;
        #pragma unroll
        for (int j = 0; j < 6; j++) {
            float4 v = *(const float4*)&sp[j * 4];
            s += v.x + v.z;
            sq += v.y + v.w;
        }
        float mu = s / 768.f;
        smu[r] = mu;
        srstd[r] = rsqrtf(sq / 768.f - mu * mu + EPSF);
    }
    for (int i = tid; i < 64 * 24; i += 512) {
        int e = i / 24, t = 208 + i % 24;
        Vt[e * 232 + t] = 0;
    }
    __syncthreads();

    // ---- phase 2: per-wave LN -> A-frag registers (strips st = sl*8+wave) --
    long tokb = (long)n * SEQ * HDIM + h * 64;
    short8 a[2][2];
    #pragma unroll
    for (int sl = 0; sl < 2; sl++) {
        int st = sl * 8 + wave;
        if (st >= 13) continue;
        int row = st * 16 + col; if (row > SEQ - 1) row = SEQ - 1;
        float mu = smu[row], rs = srstd[row];
        #pragma unroll
        for (int kt = 0; kt < 2; kt++) {
            const float* tp = &tok[tokb + (long)row * HDIM + kt * 32 + quad * 8];
            float4 v0 = *(const float4*)tp;
            float4 v1 = *(const float4*)(tp + 4);
            const float* g = &lngs[kt * 32 + quad * 8];
            const float* bb = &lnbs[kt * 32 + quad * 8];
            short8 u;
            u[0] = (short)f2bf((v0.x - mu) * rs * g[0] + bb[0]);
            u[1] = (short)f2bf((v0.y - mu) * rs * g[1] + bb[1]);
            u[2] = (short)f2bf((v0.z - mu) * rs * g[2] + bb[2]);
            u[3] = (short)f2bf((v0.w - mu) * rs * g[3] + bb[3]);
            u[4] = (short)f2bf((v1.x - mu) * rs * g[4] + bb[4]);
            u[5] = (short)f2bf((v1.y - mu) * rs * g[5] + bb[5]);
            u[6] = (short)f2bf((v1.z - mu) * rs * g[6] + bb[6]);
            u[7] = (short)f2bf((v1.w - mu) * rs * g[7] + bb[7]);
            a[sl][kt] = u;
        }
    }

    // ---- phase 3: QKV. Q/K swapped (packed b64 stores); V unswapped ----
    ushort* myP = &Ps[wave][0];
    short8 aq[2][2];
    f32x4 bQ[4], bK[4];
    #pragma unroll
    for (int et = 0; et < 4; et++) {
        bQ[et] = *(const f32x4*)&bias[0][et * 16 + quad * 4];
        bK[et] = *(const f32x4*)&bias[1][et * 16 + quad * 4];
    }
    float bV[4];
    #pragma unroll
    for (int nt = 0; nt < 4; nt++) bV[nt] = bias[2][nt * 16 + col];

    #pragma unroll
    for (int m = 0; m < 3; m++) {
        const ushort* wp = ((m == 0) ? wqs : (m == 1) ? wks : wvs) + (long)h * 4096;
        short8 b[8];
        #pragma unroll
        for (int f = 0; f < 8; f++)
            b[f] = *(const short8*)&wp[f * 512 + lane * 8];
        #pragma unroll
        for (int sl = 0; sl < 2; sl++) {
            int st = sl * 8 + wave;
            if (st >= 13) continue;
            int q0 = st * 16;
            if (m < 2) {
                // swapped: D[e = et*16+quad*4+r][token = q0+col]
                f32x4 acc[4] = {zero4, zero4, zero4, zero4};
                #pragma unroll
                for (int kt = 0; kt < 2; kt++)
                    #pragma unroll
                    for (int et = 0; et < 4; et++)
                        acc[et] = __builtin_amdgcn_mfma_f32_16x16x32_bf16(b[kt * 4 + et], a[sl][kt], acc[et], 0, 0, 0);
                if (m == 0) {
                    #pragma unroll
                    for (int et = 0; et < 4; et++) {
                        f32x4 bb = bQ[et];
                        ushort4 u = {f2bf(acc[et][0] + bb[0]), f2bf(acc[et][1] + bb[1]),
                                     f2bf(acc[et][2] + bb[2]), f2bf(acc[et][3] + bb[3])};
                        *(ushort4*)&myP[col * 72 + et * 16 + quad * 4] = u;
                    }
                    #pragma unroll
                    for (int kt = 0; kt < 2; kt++)
                        aq[sl][kt] = *(const short8*)&myP[col * 72 + kt * 32 + quad * 8];
                } else {
                    #pragma unroll
                    for (int et = 0; et < 4; et++) {
                        f32x4 bb = bK[et];
                        ushort4 u = {f2bf(acc[et][0] + bb[0]), f2bf(acc[et][1] + bb[1]),
                                     f2bf(acc[et][2] + bb[2]), f2bf(acc[et][3] + bb[3])};
                        *(ushort4*)&Ks[(q0 + col) * 72 + et * 16 + quad * 4] = u;
                    }
                }
            } else {
                // V unswapped: D[token][e]; t-contiguous packed store into Vt
                f32x4 acc[4] = {zero4, zero4, zero4, zero4};
                #pragma unroll
                for (int kt = 0; kt < 2; kt++)
                    #pragma unroll
                    for (int nt = 0; nt < 4; nt++)
                        acc[nt] = __builtin_amdgcn_mfma_f32_16x16x32_bf16(a[sl][kt], b[kt * 4 + nt], acc[nt], 0, 0, 0);
                #pragma unroll
                for (int nt = 0; nt < 4; nt++) {
                    float bb = bV[nt];
                    ushort4 u = {f2bf(acc[nt][0] + bb), f2bf(acc[nt][1] + bb),
                                 f2bf(acc[nt][2] + bb), f2bf(acc[nt][3] + bb)};
                    *(ushort4*)&Vt[(nt * 16 + col) * 232 + q0 + quad * 4] = u;
                }
            }
        }
    }
    __syncthreads();   // K, V staged across waves

    // ---- phase 4: attention per strip (scores swapped: D[key][query]) ----
    #pragma unroll
    for (int sl = 0; sl < 2; sl++) {
        int st = sl * 8 + wave;
        if (st >= 13) continue;
        int q0 = st * 16;

        // scores: sc[tt] = K_tile(tt) . Q^T -> lane holds keys tt*16+kq+r,
        // query = col. Same Ks/aq reads as before; operands swapped.
        f32x4 sc[13];
        #pragma unroll
        for (int tt = 0; tt < 13; tt++) sc[tt] = zero4;
        #pragma unroll
        for (int tt = 0; tt < 13; tt++) {
            #pragma unroll
            for (int dt = 0; dt < 2; dt++) {
                short8 bk = *(const short8*)&Ks[(tt * 16 + col) * 72 + dt * 32 + quad * 8];
                sc[tt] = __builtin_amdgcn_mfma_f32_16x16x32_bf16(bk, aq[sl][dt], sc[tt], 0, 0, 0);
            }
        }

        // softmax over keys for query=col: per-lane serial reduce over 52
        // regs, then cross-quad shuffle (lanes col, col+16, col+32, col+48).
        float mx = -1e30f;
        #pragma unroll
        for (int tt = 0; tt < 12; tt++)
            #pragma unroll
            for (int r = 0; r < 4; r++) mx = fmaxf(mx, sc[tt][r]);
        #pragma unroll
        for (int r = 0; r < 4; r++)
            if (kq + r < 5) mx = fmaxf(mx, sc[12][r]);
        mx = fmaxf(mx, __shfl_xor(mx, 16));
        mx = fmaxf(mx, __shfl_xor(mx, 32));
        float s = 0.f;
        #pragma unroll
        for (int tt = 0; tt < 12; tt++)
            #pragma unroll
            for (int r = 0; r < 4; r++) {
                float e = __expf((sc[tt][r] - mx) * SCALE);
                sc[tt][r] = e; s += e;
            }
        #pragma unroll
        for (int r = 0; r < 4; r++) {
            float e = (kq + r < 5) ? __expf((sc[12][r] - mx) * SCALE) : 0.f;
            sc[12][r] = e; s += e;
        }
        s += __shfl_xor(s, 16);
        s += __shfl_xor(s, 32);
        float rinv = 1.f / s;

        // P @ V: packed ushort4 P stores (lane's 4 consecutive keys, row=query)
        f32x4 oacc[4];
        #pragma unroll
        for (int nt = 0; nt < 4; nt++) oacc[nt] = zero4;
        #pragma unroll
        for (int kt = 0; kt < 7; kt++) {
            #pragma unroll
            for (int half = 0; half < 2; half++) {
                int tt = kt * 2 + half;
                ushort4 u = {0, 0, 0, 0};
                if (tt < 13)
                    u = (ushort4){f2bf(sc[tt][0]), f2bf(sc[tt][1]),
                                  f2bf(sc[tt][2]), f2bf(sc[tt][3])};
                *(ushort4*)&myP[col * 72 + half * 16 + kq] = u;
            }
            short8 pa = *(const short8*)&myP[col * 72 + quad * 8];
            #pragma unroll
            for (int nt = 0; nt < 4; nt++) {
                short8 vb = *(const short8*)&Vt[(nt * 16 + col) * 232 + kt * 32 + quad * 8];
                oacc[nt] = __builtin_amdgcn_mfma_f32_16x16x32_bf16(pa, vb, oacc[nt], 0, 0, 0);
            }
        }

        // rinv lives at lane col==query; redistribute to output rows quad*4+r
        float rv[4];
        #pragma unroll
        for (int r = 0; r < 4; r++) rv[r] = __shfl(rinv, kq + r, 16);

        // residual RMW + next-layer partial stats for this 64-col slice
        #pragma unroll
        for (int r = 0; r < 4; r++) {
            int row = q0 + quad * 4 + r;
            float ss = 0.f, sq = 0.f;
            if (row < SEQ) {
                #pragma unroll
                for (int nt = 0; nt < 4; nt++) {
                    long o = ((long)n * SEQ + row) * HDIM + h * 64 + nt * 16 + col;
                    float nv = tok[o] + oacc[nt][r] * rv[r];
                    tok[o] = nv;
                    ss += nv; sq += nv * nv;
                }
            }
            #pragma unroll
            for (int off = 1; off < 16; off <<= 1) {
                ss += __shfl_xor(ss, off);
                sq += __shfl_xor(sq, off);
            }
            if (row < SEQ && col == 0) {
                float* sp = &stats_out[((long)n * SEQ + row) * 24 + h * 2];
                sp[0] = ss; sp[1] = sq;
            }
        }
    }
}

// ---------------------------------------------------------------------------
// K6a: logits GEMM, fp32, wave-cooperative. grid (32 n, 8 ochunks).
// ---------------------------------------------------------------------------
__global__ __launch_bounds__(256) void k_logits(
    const float* __restrict__ tok, const float* __restrict__ W,
    const float* __restrict__ b, float* __restrict__ logits)
{
    int n = blockIdx.x, oc = blockIdx.y;
    int tid = threadIdx.x, lane = tid & 63, wave = tid >> 6;
    const float* cp = &tok[(long)n * SEQ * HDIM];
    float4 c0 = *(const float4*)&cp[lane * 4];
    float4 c1 = *(const float4*)&cp[256 + lane * 4];
    float4 c2 = *(const float4*)&cp[512 + lane * 4];
    int obeg = oc * 125, oend = obeg + 125;
    for (int o = obeg + wave; o < oend; o += 4) {
        const float* wr = &W[(long)o * HDIM];
        float4 w0 = *(const float4*)&wr[lane * 4];
        float4 w1 = *(const float4*)&wr[256 + lane * 4];
        float4 w2 = *(const float4*)&wr[512 + lane * 4];
        float s = c0.x * w0.x + c0.y * w0.y + c0.z * w0.z + c0.w * w0.w
                + c1.x * w1.x + c1.y * w1.y + c1.z * w1.z + c1.w * w1.w
                + c2.x * w2.x + c2.y * w2.y + c2.z * w2.z + c2.w * w2.w;
        #pragma unroll
        for (int off = 1; off < 64; off <<= 1) s += __shfl_xor(s, off);
        if (lane == 0) logits[n * NOUT + o] = s + b[o];
    }
}

// ---------------------------------------------------------------------------
// K6b: softmax over 1000 logits per image
// ---------------------------------------------------------------------------
__global__ __launch_bounds__(256) void k_smax(
    const float* __restrict__ logits, float* __restrict__ out)
{
    __shared__ float lg[NOUT];
    __shared__ float red[256];
    int n = blockIdx.x, tid = threadIdx.x;
    for (int o = tid; o < NOUT; o += 256) lg[o] = logits[n * NOUT + o];
    __syncthreads();
    float m = -1e30f;
    for (int o = tid; o < NOUT; o += 256) m = fmaxf(m, lg[o]);
    red[tid] = m; __syncthreads();
    for (int off = 128; off > 0; off >>= 1) {
        if (tid < off) red[tid] = fmaxf(red[tid], red[tid + off]);
        __syncthreads();
    }
    float mx = red[0];
    __syncthreads();
    float s = 0.f;
    for (int o = tid; o < NOUT; o += 256) {
        float e = __expf(lg[o] - mx);
        lg[o] = e; s += e;
    }
    red[tid] = s; __syncthreads();
    for (int off = 128; off > 0; off >>= 1) {
        if (tid < off) red[tid] += red[tid + off];
        __syncthreads();
    }
    float inv = 1.f / red[0];
    for (int o = tid; o < NOUT; o += 256) out[(long)n * NOUT + o] = lg[o] * inv;
}

// ---------------------------------------------------------------------------
extern "C" void kernel_launch(void* const* d_in, const int* in_sizes, int n_in,
                              void* d_out, int out_size, void* d_ws, size_t ws_size,
                              hipStream_t stream)
{
    const float* images  = (const float*)d_in[0];
    const float* conv_w  = (const float*)d_in[1];
    const float* conv_b  = (const float*)d_in[2];
    const float* bn_g    = (const float*)d_in[3];
    const float* bn_b    = (const float*)d_in[4];
    const float* bn_m    = (const float*)d_in[5];
    const float* bn_v    = (const float*)d_in[6];
    const float* map_w   = (const float*)d_in[7];
    const float* map_b   = (const float*)d_in[8];
    const float* cls_tok = (const float*)d_in[9];
    const float* ln_g    = (const float*)d_in[10];
    const float* ln_b    = (const float*)d_in[11];
    const float* wq      = (const float*)d_in[12];
    const float* bq      = (const float*)d_in[13];
    const float* wk      = (const float*)d_in[14];
    const float* bk      = (const float*)d_in[15];
    const float* wv      = (const float*)d_in[16];
    const float* bv      = (const float*)d_in[17];
    const float* mlp_w   = (const float*)d_in[18];
    const float* mlp_b   = (const float*)d_in[19];
    float* out = (float*)d_out;

    const long SZ_X   = (long)NPATCH * IND;       // ushorts
    const long SZ_W   = (long)HDIM * IND;         // ushorts
    const long SZ_WS  = (long)3 * 144 * 4096;     // ushorts
    const long SZ_POS = (long)SEQ * HDIM;         // floats
    const long SZ_TOK = (long)NTOK * HDIM;        // floats
    const long SZ_ST  = (long)NTOK * 24;          // floats

    ushort* Xbf   = (ushort*)d_ws;
    ushort* Wbf   = Xbf + SZ_X;
    ushort* Wswz  = Wbf + SZ_W;
    float*  pos   = (float*)(Wswz + SZ_WS);
    float*  tok   = pos + SZ_POS;
    float*  sta   = tok + SZ_TOK;
    float*  stb   = sta + SZ_ST;
    float* logits = (float*)Xbf;                  // Xbf dead after k_embed

    k_prep<<<1693, 256, 0, stream>>>(map_w, Wbf, wq, wk, wv, Wswz,
                                     pos, cls_tok, tok);
    k_conv_patch<<<NPATCH / 2, 320, 0, stream>>>(images, conv_w, conv_b, bn_g,
                                                 bn_b, bn_m, bn_v, Xbf);
    dim3 ge(49, 12);
    k_embed<<<ge, 256, 0, stream>>>(Xbf, Wbf, map_b, pos, tok);

    k_lnstats0<<<NTOK / 4, 256, 0, stream>>>(tok, sta);
    for (int l = 0; l < LLAYERS; l++) {
        float* srd = (l & 1) ? stb : sta;
        float* swr = (l & 1) ? sta : stb;
        dim3 gl(12, 32);
        k_layer<<<gl, 512, 0, stream>>>(tok, srd, swr,
            ln_g + (long)l * HDIM, ln_b + (long)l * HDIM,
            Wswz + (long)(0 * 144 + l * 12) * 4096, bq + (long)l * NHEAD * DHEAD,
            Wswz + (long)(1 * 144 + l * 12) * 4096, bk + (long)l * NHEAD * DHEAD,
            Wswz + (long)(2 * 144 + l * 12) * 4096, bv + (long)l * NHEAD * DHEAD);
    }
    dim3 glo(BB, 8);
    k_logits<<<glo, 256, 0, stream>>>(tok, mlp_w, mlp_b, logits);
    k_smax<<<BB, 256, 0, stream>>>(logits, out);
}

// Round 13
// 512.255 us; speedup vs baseline: 1.0088x; 1.0088x over previous
//
#include <hip/hip_runtime.h>

#define BB 32
#define LLAYERS 12
#define HDIM 768
#define NHEAD 12
#define DHEAD 64
#define SEQ 197
#define IND 800
#define NOUT 1000
#define EPSF 1e-5f
#define NTOK (BB * SEQ)     // 6304
#define NPATCH (BB * 196)   // 6272
#define SCALE 0.125f        // 1/sqrt(64)
#define HSTRIDE (SEQ * DHEAD)   // 12608 floats per (n,h) slice

typedef __attribute__((ext_vector_type(4))) float f32x4;
typedef __attribute__((ext_vector_type(8))) short short8;

static __device__ __forceinline__ ushort f2bf(float f) {
    union { float f; unsigned u; } v; v.f = f;
    unsigned r = v.u + 0x7FFFu + ((v.u >> 16) & 1u);   // round-to-nearest-even
    return (ushort)(r >> 16);
}

static __device__ __forceinline__ void gload_lds16(const void* g, void* l) {
    __builtin_amdgcn_global_load_lds(
        (const __attribute__((address_space(1))) void*)g,
        (__attribute__((address_space(3))) void*)l, 16, 0, 0);
}

// tok layout is HEAD-MAJOR: tok[((n*12 + h) * 197 + s) * 64 + d]
// so each k_layer block (n,h) owns one contiguous 50 KB slice.

// ---------------------------------------------------------------------------
// K0: fused prep — map_w cvt (blocks 0..599), wqkv swizzle (600..1463),
// pos table (1464..1660), cls rows (1661..1692). All independent.
// ---------------------------------------------------------------------------
__global__ __launch_bounds__(256) void k_prep(
    const float* __restrict__ map_w, ushort* __restrict__ Wbf,
    const float* __restrict__ wq, const float* __restrict__ wk,
    const float* __restrict__ wv, ushort* __restrict__ Wswz,
    float* __restrict__ pos, const float* __restrict__ cls_tok,
    float* __restrict__ tok)
{
    int b = blockIdx.x;
    if (b < 600) {
        int i = b * 256 + threadIdx.x;
        if (i < (HDIM * IND) / 4) {
            float4 v = *(const float4*)&map_w[i * 4];
            ushort4 u = {f2bf(v.x), f2bf(v.y), f2bf(v.z), f2bf(v.w)};
            *(ushort4*)&Wbf[i * 4] = u;
        }
    } else if (b < 1464) {
        int t = (b - 600) * 256 + threadIdx.x;     // < 3*144*512 exactly
        int lane = t & 63;
        int rest = t >> 6;
        int ktnt = rest & 7;
        int mlh = rest >> 3;
        int h = mlh % 12, ml = mlh / 12;
        int l = ml % 12, m = ml / 12;
        int nt = ktnt & 3, kt = ktnt >> 2;
        int e = nt * 16 + (lane & 15);
        int d = kt * 32 + (lane >> 4) * 8;
        const float* src = ((m == 0) ? wq : (m == 1) ? wk : wv)
                           + (((long)l * 12 + h) * 64 + e) * 64 + d;
        float4 a = *(const float4*)src;
        float4 bb = *(const float4*)(src + 4);
        short8 u;
        u[0] = (short)f2bf(a.x); u[1] = (short)f2bf(a.y);
        u[2] = (short)f2bf(a.z); u[3] = (short)f2bf(a.w);
        u[4] = (short)f2bf(bb.x); u[5] = (short)f2bf(bb.y);
        u[6] = (short)f2bf(bb.z); u[7] = (short)f2bf(bb.w);
        *(short8*)&Wswz[(long)mlh * 4096 + ktnt * 512 + lane * 8] = u;
    } else if (b < 1661) {
        int s = b - 1464;
        for (int e = threadIdx.x; e < HDIM; e += 256) {
            float freq = expf((float)(e & ~1) * (-9.210340371976184f / 768.0f));
            float ang = (float)s * freq;
            pos[s * HDIM + e] = (e & 1) ? cosf(ang) : sinf(ang);
        }
    } else {
        int n = b - 1661;                          // 32 cls rows; pos[0,e]=e&1
        for (int e = threadIdx.x; e < HDIM; e += 256) {
            int h = e >> 6, d = e & 63;
            tok[(long)(n * 12 + h) * HSTRIDE + d] =
                cls_tok[e] + ((e & 1) ? 1.0f : 0.0f);
        }
    }
}

// ---------------------------------------------------------------------------
// K1: conv + BN + ReLU + patchify -> Xbf. 2 patches/block, 320 threads.
// R8 version: stride-21 rows give ph-bank spread {0,20,8,28,16} — measured
// ZERO bank conflicts. Do NOT pad.
// ---------------------------------------------------------------------------
__global__ __launch_bounds__(320) void k_conv_patch(
    const float* __restrict__ img, const float* __restrict__ cw,
    const float* __restrict__ cb, const float* __restrict__ bg,
    const float* __restrict__ bbias, const float* __restrict__ bm,
    const float* __restrict__ bvv, ushort* __restrict__ X)
{
    __shared__ float tile[2][3][21][21];
    __shared__ float w[2400];
    __shared__ float scale[32], shift[32];
    int tid = threadIdx.x;

    for (int i = tid; i < 2400; i += 320) w[i] = cw[i];
    if (tid < 32) {
        float sc = bg[tid] * rsqrtf(bvv[tid] + EPSF);
        scale[tid] = sc;
        shift[tid] = (cb[tid] - bm[tid]) * sc + bbias[tid];
    }
    for (int i = tid; i < 2 * 3 * 441; i += 320) {
        int pp = i / 1323, j = i % 1323;
        int c = j / 441, r = (j / 21) % 21, cc = j % 21;
        int gp = blockIdx.x * 2 + pp;
        int n = gp / 196, p = gp % 196;
        int h0 = (p / 14) * 20 - 1, w0 = (p % 14) * 20 - 1;
        int gh = h0 + r, gw = w0 + cc;
        float v = 0.f;
        if (gh >= 0 && gh < 280 && gw >= 0 && gw < 280)
            v = img[((long)(n * 3 + c) * 280 + gh) * 280 + gw];
        tile[pp][c][r][cc] = v;
    }
    __syncthreads();

    int pp = tid / 160, u = tid % 160;
    int c = u / 5, ph = u % 5;
    float acc[5] = {0.f, 0.f, 0.f, 0.f, 0.f};
    const float* wp = &w[c * 75];
    #pragma unroll
    for (int ci = 0; ci < 3; ci++) {
        #pragma unroll
        for (int kh = 0; kh < 5; kh++) {
            const float* row = &tile[pp][ci][ph * 4 + kh][0];
            float rv[21];
            #pragma unroll
            for (int j = 0; j < 21; j++) rv[j] = row[j];
            #pragma unroll
            for (int kw = 0; kw < 5; kw++) {
                float wv = wp[ci * 25 + kh * 5 + kw];
                #pragma unroll
                for (int pw = 0; pw < 5; pw++)
                    acc[pw] += rv[pw * 4 + kw] * wv;
            }
        }
    }
    int gp = blockIdx.x * 2 + pp;
    long ob = (long)gp * 800 + c * 25 + ph * 5;
    #pragma unroll
    for (int pw = 0; pw < 5; pw++) {
        float val = acc[pw] * scale[c] + shift[c];
        X[ob + pw] = f2bf(fmaxf(val, 0.f));
    }
}

// ---------------------------------------------------------------------------
// K2: patch embed GEMM, bf16 MFMA. Writes head-major tok (e0 block = head
// blockIdx.y; d = wn + nt*16 + col).
// ---------------------------------------------------------------------------
__global__ __launch_bounds__(256, 2) void k_embed(
    const ushort* __restrict__ Xg, const ushort* __restrict__ Wg,
    const float* __restrict__ bias, const float* __restrict__ pos,
    float* __restrict__ tok)
{
    __shared__ __align__(16) ushort As[128 * 32];
    __shared__ __align__(16) ushort Bs[64 * 32];
    int m0 = blockIdx.x * 128, e0 = blockIdx.y * 64;
    int tid = threadIdx.x, lane = tid & 63, wave = tid >> 6;
    int col = lane & 15, quad = lane >> 4;
    int wm = (wave & 1) * 64, wn = (wave >> 1) * 32;
    int lr = lane >> 2, lc = (lane & 3) * 8;
    f32x4 zero4 = {0.f, 0.f, 0.f, 0.f};
    f32x4 acc[4][2];
    #pragma unroll
    for (int mt = 0; mt < 4; mt++)
        #pragma unroll
        for (int nt = 0; nt < 2; nt++) acc[mt][nt] = zero4;

    for (int k0 = 0; k0 < 800; k0 += 32) {
        __syncthreads();
        #pragma unroll
        for (int i = 0; i < 2; i++) {
            int c = wave * 2 + i;
            gload_lds16(&Xg[(long)(m0 + c * 16 + lr) * 800 + k0 + lc], &As[c * 512]);
        }
        {
            int c = wave;
            gload_lds16(&Wg[(long)(e0 + c * 16 + lr) * 800 + k0 + lc], &Bs[c * 512]);
        }
        __syncthreads();
        short8 a[4], b[2];
        #pragma unroll
        for (int mt = 0; mt < 4; mt++)
            a[mt] = *(const short8*)&As[(wm + mt * 16 + col) * 32 + quad * 8];
        #pragma unroll
        for (int nt = 0; nt < 2; nt++)
            b[nt] = *(const short8*)&Bs[(wn + nt * 16 + col) * 32 + quad * 8];
        #pragma unroll
        for (int mt = 0; mt < 4; mt++)
            #pragma unroll
            for (int nt = 0; nt < 2; nt++)
                acc[mt][nt] = __builtin_amdgcn_mfma_f32_16x16x32_bf16(a[mt], b[nt], acc[mt][nt], 0, 0, 0);
    }
    int hh = blockIdx.y;
    #pragma unroll
    for (int mt = 0; mt < 4; mt++) {
        #pragma unroll
        for (int r = 0; r < 4; r++) {
            int m = m0 + wm + mt * 16 + quad * 4 + r;
            int n = m / 196, s = m - n * 196 + 1;
            long rowb = ((long)(n * 12 + hh) * SEQ + s) * DHEAD;
            #pragma unroll
            for (int nt = 0; nt < 2; nt++) {
                int d = wn + nt * 16 + col;
                int e = e0 + d;
                tok[rowb + d] = acc[mt][nt][r] + bias[e] + pos[s * HDIM + e];
            }
        }
    }
}

// ---------------------------------------------------------------------------
// K3: initial LN partial-stats (layer 0), head-major tok
// ---------------------------------------------------------------------------
__global__ __launch_bounds__(256) void k_lnstats0(
    const float* __restrict__ tok, float* __restrict__ stats_out)
{
    int tid = threadIdx.x, lane = tid & 63, wave = tid >> 6;
    int row = blockIdx.x * 4 + wave;          // NTOK = 4*1576 exact
    int n = row / SEQ, sidx = row - n * SEQ;
    float s = 0.f, sq = 0.f;
    #pragma unroll
    for (int k = 0; k < 3; k++) {
        int i = k * 256 + lane * 4;
        int h = i >> 6, d = i & 63;
        const float* p = &tok[((long)(n * 12 + h) * SEQ + sidx) * DHEAD + d];
        float4 v = *(const float4*)p;
        s += v.x + v.y + v.z + v.w;
        sq += v.x * v.x + v.y * v.y + v.z * v.z + v.w * v.w;
    }
    #pragma unroll
    for (int off = 1; off < 64; off <<= 1) {
        s += __shfl_xor(s, off);
        sq += __shfl_xor(sq, off);
    }
    float* sp = &stats_out[(long)row * 24];
    if (lane == 0) { sp[0] = s; sp[1] = sq; }
    if (lane >= 2 && lane < 24) sp[lane] = 0.f;
}

// ---------------------------------------------------------------------------
// K4: FUSED transformer layer — 512 thr = 8 waves, 2 blocks/CU (~81 KB LDS).
// Head-major tok: this block's slice is contiguous 50 KB -> coalesced
// phase-2 loads and epilogue RMW. grid (12, 32).
// ---------------------------------------------------------------------------
__global__ __launch_bounds__(512, 4) void k_layer(
    float* __restrict__ tok,
    const float* __restrict__ stats_in, float* __restrict__ stats_out,
    const float* __restrict__ lng, const float* __restrict__ lnb,
    const ushort* __restrict__ wqs, const float* __restrict__ bqp,
    const ushort* __restrict__ wks, const float* __restrict__ bkp,
    const ushort* __restrict__ wvs, const float* __restrict__ bvp)
{
    __shared__ __align__(16) ushort Ks[208 * 72];   // 29.9 KB
    __shared__ __align__(16) ushort Vt[64 * 232];   // 29.7 KB
    __shared__ __align__(16) ushort Ps[8][16 * 72]; // 18.4 KB per-wave scratch
    __shared__ float smu[208], srstd[208];
    __shared__ __align__(16) float bias[3][64];
    __shared__ float lngs[64], lnbs[64];

    int h = blockIdx.x, n = blockIdx.y;
    int tid = threadIdx.x, lane = tid & 63, wave = tid >> 6;   // wave 0..7
    int col = lane & 15, quad = lane >> 4;
    int kq = quad * 4;                // key sub-offset after score swap
    f32x4 zero4 = {0.f, 0.f, 0.f, 0.f};

    // ---- phase 1: bias + ln params + per-row stats reduce + Vt pad ----
    if (tid < 192) {
        int m = tid >> 6, e = tid & 63;
        bias[m][e] = ((m == 0) ? bqp : (m == 1) ? bkp : bvp)[h * 64 + e];
    } else if (tid < 256) {
        lngs[tid - 192] = lng[h * 64 + tid - 192];
    } else if (tid < 320) {
        lnbs[tid - 256] = lnb[h * 64 + tid - 256];
    }
    for (int r = tid; r < SEQ; r += 512) {
        const float* sp = &stats_in[((long)n * SEQ + r) * 24];
        float s = 0.f, sq = 0.f;
        #pragma unroll
        for (int j = 0; j < 6; j++) {
            float4 v = *(const float4*)&sp[j * 4];
            s += v.x + v.z;
            sq += v.y + v.w;
        }
        float mu = s / 768.f;
        smu[r] = mu;
        srstd[r] = rsqrtf(sq / 768.f - mu * mu + EPSF);
    }
    for (int i = tid; i < 64 * 24; i += 512) {
        int e = i / 24, t = 208 + i % 24;
        Vt[e * 232 + t] = 0;
    }
    __syncthreads();

    // ---- phase 2: per-wave LN -> A-frag registers (strips st = sl*8+wave) --
    long tokb = (long)(n * 12 + h) * HSTRIDE;     // contiguous 50 KB slice
    short8 a[2][2];
    #pragma unroll
    for (int sl = 0; sl < 2; sl++) {
        int st = sl * 8 + wave;
        if (st >= 13) continue;
        int row = st * 16 + col; if (row > SEQ - 1) row = SEQ - 1;
        float mu = smu[row], rs = srstd[row];
        #pragma unroll
        for (int kt = 0; kt < 2; kt++) {
            const float* tp = &tok[tokb + (long)row * DHEAD + kt * 32 + quad * 8];
            float4 v0 = *(const float4*)tp;
            float4 v1 = *(const float4*)(tp + 4);
            const float* g = &lngs[kt * 32 + quad * 8];
            const float* bb = &lnbs[kt * 32 + quad * 8];
            short8 u;
            u[0] = (short)f2bf((v0.x - mu) * rs * g[0] + bb[0]);
            u[1] = (short)f2bf((v0.y - mu) * rs * g[1] + bb[1]);
            u[2] = (short)f2bf((v0.z - mu) * rs * g[2] + bb[2]);
            u[3] = (short)f2bf((v0.w - mu) * rs * g[3] + bb[3]);
            u[4] = (short)f2bf((v1.x - mu) * rs * g[4] + bb[4]);
            u[5] = (short)f2bf((v1.y - mu) * rs * g[5] + bb[5]);
            u[6] = (short)f2bf((v1.z - mu) * rs * g[6] + bb[6]);
            u[7] = (short)f2bf((v1.w - mu) * rs * g[7] + bb[7]);
            a[sl][kt] = u;
        }
    }

    // ---- phase 3: QKV. Q/K swapped (packed b64 stores); V unswapped ----
    ushort* myP = &Ps[wave][0];
    short8 aq[2][2];
    f32x4 bQ[4], bK[4];
    #pragma unroll
    for (int et = 0; et < 4; et++) {
        bQ[et] = *(const f32x4*)&bias[0][et * 16 + quad * 4];
        bK[et] = *(const f32x4*)&bias[1][et * 16 + quad * 4];
    }
    float bV[4];
    #pragma unroll
    for (int nt = 0; nt < 4; nt++) bV[nt] = bias[2][nt * 16 + col];

    #pragma unroll
    for (int m = 0; m < 3; m++) {
        const ushort* wp = ((m == 0) ? wqs : (m == 1) ? wks : wvs) + (long)h * 4096;
        short8 b[8];
        #pragma unroll
        for (int f = 0; f < 8; f++)
            b[f] = *(const short8*)&wp[f * 512 + lane * 8];
        #pragma unroll
        for (int sl = 0; sl < 2; sl++) {
            int st = sl * 8 + wave;
            if (st >= 13) continue;
            int q0 = st * 16;
            if (m < 2) {
                // swapped: D[e = et*16+quad*4+r][token = q0+col]
                f32x4 acc[4] = {zero4, zero4, zero4, zero4};
                #pragma unroll
                for (int kt = 0; kt < 2; kt++)
                    #pragma unroll
                    for (int et = 0; et < 4; et++)
                        acc[et] = __builtin_amdgcn_mfma_f32_16x16x32_bf16(b[kt * 4 + et], a[sl][kt], acc[et], 0, 0, 0);
                if (m == 0) {
                    #pragma unroll
                    for (int et = 0; et < 4; et++) {
                        f32x4 bb = bQ[et];
                        ushort4 u = {f2bf(acc[et][0] + bb[0]), f2bf(acc[et][1] + bb[1]),
                                     f2bf(acc[et][2] + bb[2]), f2bf(acc[et][3] + bb[3])};
                        *(ushort4*)&myP[col * 72 + et * 16 + quad * 4] = u;
                    }
                    #pragma unroll
                    for (int kt = 0; kt < 2; kt++)
                        aq[sl][kt] = *(const short8*)&myP[col * 72 + kt * 32 + quad * 8];
                } else {
                    #pragma unroll
                    for (int et = 0; et < 4; et++) {
                        f32x4 bb = bK[et];
                        ushort4 u = {f2bf(acc[et][0] + bb[0]), f2bf(acc[et][1] + bb[1]),
                                     f2bf(acc[et][2] + bb[2]), f2bf(acc[et][3] + bb[3])};
                        *(ushort4*)&Ks[(q0 + col) * 72 + et * 16 + quad * 4] = u;
                    }
                }
            } else {
                // V unswapped: D[token][e]; t-contiguous packed store into Vt
                f32x4 acc[4] = {zero4, zero4, zero4, zero4};
                #pragma unroll
                for (int kt = 0; kt < 2; kt++)
                    #pragma unroll
                    for (int nt = 0; nt < 4; nt++)
                        acc[nt] = __builtin_amdgcn_mfma_f32_16x16x32_bf16(a[sl][kt], b[kt * 4 + nt], acc[nt], 0, 0, 0);
                #pragma unroll
                for (int nt = 0; nt < 4; nt++) {
                    float bb = bV[nt];
                    ushort4 u = {f2bf(acc[nt][0] + bb), f2bf(acc[nt][1] + bb),
                                 f2bf(acc[nt][2] + bb), f2bf(acc[nt][3] + bb)};
                    *(ushort4*)&Vt[(nt * 16 + col) * 232 + q0 + quad * 4] = u;
                }
            }
        }
    }
    __syncthreads();   // K, V staged across waves

    // ---- phase 4: attention per strip (scores swapped: D[key][query]) ----
    #pragma unroll
    for (int sl = 0; sl < 2; sl++) {
        int st = sl * 8 + wave;
        if (st >= 13) continue;
        int q0 = st * 16;

        f32x4 sc[13];
        #pragma unroll
        for (int tt = 0; tt < 13; tt++) sc[tt] = zero4;
        #pragma unroll
        for (int tt = 0; tt < 13; tt++) {
            #pragma unroll
            for (int dt = 0; dt < 2; dt++) {
                short8 bk = *(const short8*)&Ks[(tt * 16 + col) * 72 + dt * 32 + quad * 8];
                sc[tt] = __builtin_amdgcn_mfma_f32_16x16x32_bf16(bk, aq[sl][dt], sc[tt], 0, 0, 0);
            }
        }

        // softmax over keys for query=col
        float mx = -1e30f;
        #pragma unroll
        for (int tt = 0; tt < 12; tt++)
            #pragma unroll
            for (int r = 0; r < 4; r++) mx = fmaxf(mx, sc[tt][r]);
        #pragma unroll
        for (int r = 0; r < 4; r++)
            if (kq + r < 5) mx = fmaxf(mx, sc[12][r]);
        mx = fmaxf(mx, __shfl_xor(mx, 16));
        mx = fmaxf(mx, __shfl_xor(mx, 32));
        float s = 0.f;
        #pragma unroll
        for (int tt = 0; tt < 12; tt++)
            #pragma unroll
            for (int r = 0; r < 4; r++) {
                float e = __expf((sc[tt][r] - mx) * SCALE);
                sc[tt][r] = e; s += e;
            }
        #pragma unroll
        for (int r = 0; r < 4; r++) {
            float e = (kq + r < 5) ? __expf((sc[12][r] - mx) * SCALE) : 0.f;
            sc[12][r] = e; s += e;
        }
        s += __shfl_xor(s, 16);
        s += __shfl_xor(s, 32);
        float rinv = 1.f / s;

        // P @ V (packed P stores)
        f32x4 oacc[4];
        #pragma unroll
        for (int nt = 0; nt < 4; nt++) oacc[nt] = zero4;
        #pragma unroll
        for (int kt = 0; kt < 7; kt++) {
            #pragma unroll
            for (int half = 0; half < 2; half++) {
                int tt = kt * 2 + half;
                ushort4 u = {0, 0, 0, 0};
                if (tt < 13)
                    u = (ushort4){f2bf(sc[tt][0]), f2bf(sc[tt][1]),
                                  f2bf(sc[tt][2]), f2bf(sc[tt][3])};
                *(ushort4*)&myP[col * 72 + half * 16 + kq] = u;
            }
            short8 pa = *(const short8*)&myP[col * 72 + quad * 8];
            #pragma unroll
            for (int nt = 0; nt < 4; nt++) {
                short8 vb = *(const short8*)&Vt[(nt * 16 + col) * 232 + kt * 32 + quad * 8];
                oacc[nt] = __builtin_amdgcn_mfma_f32_16x16x32_bf16(pa, vb, oacc[nt], 0, 0, 0);
            }
        }

        float rv[4];
        #pragma unroll
        for (int r = 0; r < 4; r++) rv[r] = __shfl(rinv, kq + r, 16);

        // residual RMW (coalesced 64-float rows) + next-layer partial stats
        #pragma unroll
        for (int r = 0; r < 4; r++) {
            int row = q0 + quad * 4 + r;
            float ss = 0.f, sq = 0.f;
            if (row < SEQ) {
                #pragma unroll
                for (int nt = 0; nt < 4; nt++) {
                    long o = tokb + (long)row * DHEAD + nt * 16 + col;
                    float nv = tok[o] + oacc[nt][r] * rv[r];
                    tok[o] = nv;
                    ss += nv; sq += nv * nv;
                }
            }
            #pragma unroll
            for (int off = 1; off < 16; off <<= 1) {
                ss += __shfl_xor(ss, off);
                sq += __shfl_xor(sq, off);
            }
            if (row < SEQ && col == 0) {
                float* sp = &stats_out[((long)n * SEQ + row) * 24 + h * 2];
                sp[0] = ss; sp[1] = sq;
            }
        }
    }
}

// ---------------------------------------------------------------------------
// K6a: logits GEMM, fp32, wave-cooperative. grid (32 n, 8 ochunks).
// cls row gathered from head-major layout (s = 0).
// ---------------------------------------------------------------------------
__global__ __launch_bounds__(256) void k_logits(
    const float* __restrict__ tok, const float* __restrict__ W,
    const float* __restrict__ b, float* __restrict__ logits)
{
    int n = blockIdx.x, oc = blockIdx.y;
    int tid = threadIdx.x, lane = tid & 63, wave = tid >> 6;
    float4 c[3];
    #pragma unroll
    for (int k = 0; k < 3; k++) {
        int i = k * 256 + lane * 4;
        int hh = i >> 6, d = i & 63;
        c[k] = *(const float4*)&tok[(long)(n * 12 + hh) * HSTRIDE + d];
    }
    int obeg = oc * 125, oend = obeg + 125;
    for (int o = obeg + wave; o < oend; o += 4) {
        const float* wr = &W[(long)o * HDIM];
        float4 w0 = *(const float4*)&wr[lane * 4];
        float4 w1 = *(const float4*)&wr[256 + lane * 4];
        float4 w2 = *(const float4*)&wr[512 + lane * 4];
        float s = c[0].x * w0.x + c[0].y * w0.y + c[0].z * w0.z + c[0].w * w0.w
                + c[1].x * w1.x + c[1].y * w1.y + c[1].z * w1.z + c[1].w * w1.w
                + c[2].x * w2.x + c[2].y * w2.y + c[2].z * w2.z + c[2].w * w2.w;
        #pragma unroll
        for (int off = 1; off < 64; off <<= 1) s += __shfl_xor(s, off);
        if (lane == 0) logits[n * NOUT + o] = s + b[o];
    }
}

// ---------------------------------------------------------------------------
// K6b: softmax over 1000 logits per image
// ---------------------------------------------------------------------------
__global__ __launch_bounds__(256) void k_smax(
    const float* __restrict__ logits, float* __restrict__ out)
{
    __shared__ float lg[NOUT];
    __shared__ float red[256];
    int n = blockIdx.x, tid = threadIdx.x;
    for (int o = tid; o < NOUT; o += 256) lg[o] = logits[n * NOUT + o];
    __syncthreads();
    float m = -1e30f;
    for (int o = tid; o < NOUT; o += 256) m = fmaxf(m, lg[o]);
    red[tid] = m; __syncthreads();
    for (int off = 128; off > 0; off >>= 1) {
        if (tid < off) red[tid] = fmaxf(red[tid], red[tid + off]);
        __syncthreads();
    }
    float mx = red[0];
    __syncthreads();
    float s = 0.f;
    for (int o = tid; o < NOUT; o += 256) {
        float e = __expf(lg[o] - mx);
        lg[o] = e; s += e;
    }
    red[tid] = s; __syncthreads();
    for (int off = 128; off > 0; off >>= 1) {
        if (tid < off) red[tid] += red[tid + off];
        __syncthreads();
    }
    float inv = 1.f / red[0];
    for (int o = tid; o < NOUT; o += 256) out[(long)n * NOUT + o] = lg[o] * inv;
}

// ---------------------------------------------------------------------------
extern "C" void kernel_launch(void* const* d_in, const int* in_sizes, int n_in,
                              void* d_out, int out_size, void* d_ws, size_t ws_size,
                              hipStream_t stream)
{
    const float* images  = (const float*)d_in[0];
    const float* conv_w  = (const float*)d_in[1];
    const float* conv_b  = (const float*)d_in[2];
    const float* bn_g    = (const float*)d_in[3];
    const float* bn_b    = (const float*)d_in[4];
    const float* bn_m    = (const float*)d_in[5];
    const float* bn_v    = (const float*)d_in[6];
    const float* map_w   = (const float*)d_in[7];
    const float* map_b   = (const float*)d_in[8];
    const float* cls_tok = (const float*)d_in[9];
    const float* ln_g    = (const float*)d_in[10];
    const float* ln_b    = (const float*)d_in[11];
    const float* wq      = (const float*)d_in[12];
    const float* bq      = (const float*)d_in[13];
    const float* wk      = (const float*)d_in[14];
    const float* bk      = (const float*)d_in[15];
    const float* wv      = (const float*)d_in[16];
    const float* bv      = (const float*)d_in[17];
    const float* mlp_w   = (const float*)d_in[18];
    const float* mlp_b   = (const float*)d_in[19];
    float* out = (float*)d_out;

    const long SZ_X   = (long)NPATCH * IND;       // ushorts
    const long SZ_W   = (long)HDIM * IND;         // ushorts
    const long SZ_WS  = (long)3 * 144 * 4096;     // ushorts
    const long SZ_POS = (long)SEQ * HDIM;         // floats
    const long SZ_TOK = (long)NTOK * HDIM;        // floats
    const long SZ_ST  = (long)NTOK * 24;          // floats

    ushort* Xbf   = (ushort*)d_ws;
    ushort* Wbf   = Xbf + SZ_X;
    ushort* Wswz  = Wbf + SZ_W;
    float*  pos   = (float*)(Wswz + SZ_WS);
    float*  tok   = pos + SZ_POS;
    float*  sta   = tok + SZ_TOK;
    float*  stb   = sta + SZ_ST;
    float* logits = (float*)Xbf;                  // Xbf dead after k_embed

    k_prep<<<1693, 256, 0, stream>>>(map_w, Wbf, wq, wk, wv, Wswz,
                                     pos, cls_tok, tok);
    k_conv_patch<<<NPATCH / 2, 320, 0, stream>>>(images, conv_w, conv_b, bn_g,
                                                 bn_b, bn_m, bn_v, Xbf);
    dim3 ge(49, 12);
    k_embed<<<ge, 256, 0, stream>>>(Xbf, Wbf, map_b, pos, tok);

    k_lnstats0<<<NTOK / 4, 256, 0, stream>>>(tok, sta);
    for (int l = 0; l < LLAYERS; l++) {
        float* srd = (l & 1) ? stb : sta;
        float* swr = (l & 1) ? sta : stb;
        dim3 gl(12, 32);
        k_layer<<<gl, 512, 0, stream>>>(tok, srd, swr,
            ln_g + (long)l * HDIM, ln_b + (long)l * HDIM,
            Wswz + (long)(0 * 144 + l * 12) * 4096, bq + (long)l * NHEAD * DHEAD,
            Wswz + (long)(1 * 144 + l * 12) * 4096, bk + (long)l * NHEAD * DHEAD,
            Wswz + (long)(2 * 144 + l * 12) * 4096, bv + (long)l * NHEAD * DHEAD);
    }
    dim3 glo(BB, 8);
    k_logits<<<glo, 256, 0, stream>>>(tok, mlp_w, mlp_b, logits);
    k_smax<<<BB, 256, 0, stream>>>(logits, out);
}